// Round 12
// baseline (428.511 us; speedup 1.0000x reference)
//
#include <hip/hip_runtime.h>

// Problem constants (from reference)
#define B_      128
#define NPIX    32      // N = M = 32
#define NNEO    30      // N-2
#define CSTATE  19      // real state channels
#define CPAD    20      // padded channel stride (16B-aligned pixel blocks)
#define OUTD    21      // OUT_DIM
#define ITERS   10
#define THRESHV 0.0007f

#define STATE_ELEMS_PAD (B_ * NPIX * NPIX * CPAD)  // 2,621,440 floats per buffer
#define NCELLS      (B_ * NNEO * NNEO)             // 115,200
#define CLASS_ELEMS (NCELLS * 3)                   // 345,600
#define HSTRIDE 31    // s_h cell stride: gcd(31,32)=1 -> conflict-free

// ---------------------------------------------------------------------------
// Border zeroing is merged into nca_step0 (saves one launch). Interior pixels
// are fully written by each step before being read; garbage pad channel 19 is
// read-and-discarded, never used in arithmetic. perc needs no init.
// ---------------------------------------------------------------------------

// ---------------------------------------------------------------------------
// Step 0 standalone (R9/R10: removes the FIRST-template instantiation that
// kept drawing a degenerate register allocation). State all-zero at t=0.
// Also zeroes the borders of BOTH state buffers (merged nca_init).
// ---------------------------------------------------------------------------
__global__ __launch_bounds__(1024, 8)
void nca_step0(const float* __restrict__ img,
               const float* __restrict__ W1, const float* __restrict__ b1,
               const float* __restrict__ W2, const float* __restrict__ b2,
               const float* __restrict__ W3, const float* __restrict__ b3,
               float* __restrict__ stateA, float* __restrict__ stateB,
               int* __restrict__ perc) {
    __shared__ float s_img[NPIX * NPIX];            // 4 KB
    __shared__ float s_h[240 * HSTRIDE];            // 29.8 KB

    const int b   = blockIdx.y;
    const int rg  = blockIdx.x;
    const int i0  = (rg < 2) ? rg * 8 : 16 + (rg - 2) * 7;
    const int nr  = (rg < 2) ? 8 : 7;
    const int tid = threadIdx.x;
    const int qh  = __builtin_amdgcn_readfirstlane(tid >> 8);   // wave-uniform
    const int cell = tid & 255;
    const int qoff = (qh == 0) ? 0 : (qh == 1) ? 8 : (qh == 2) ? 14 : 22;
    const int off3 = 5 * qh;

    // merged init: zero borders of both buffers (124 pixels * 20 ch, /4 blocks)
    {
        const int per = (124 * CPAD) / 4;   // 620
        if (tid < per) {
            int idx = rg * per + tid;       // 0..2479
            int c    = idx % CPAD;
            int bc   = idx / CPAD;          // border cell 0..123
            int bi, bj;
            if (bc < 32)      { bi = 0;  bj = bc; }
            else if (bc < 64) { bi = 31; bj = bc - 32; }
            else { int k = bc - 64; bi = 1 + (k >> 1); bj = (k & 1) ? 31 : 0; }
            size_t off = (((size_t)b * NPIX + bi) * NPIX + bj) * CPAD + c;
            stateA[off] = 0.0f;
            stateB[off] = 0.0f;
        }
    }

    if (tid < NPIX * NPIX / 4) {
        ((float4*)s_img)[tid] = ((const float4*)(img + (size_t)b * NPIX * NPIX))[tid];
    }
    __syncthreads();

    const int cells = nr * NNEO;
    const bool active = cell < cells;

    int r = 0, j = 0, i = 0, gcell = 0, px = 0, py = 0;
    if (active) {
        r = cell / NNEO;
        j = cell % NNEO;
        i = i0 + r;
        gcell = (b * NNEO + i) * NNEO + j;
        px = i; py = j;
    }

    float h1[8];
    {
        const float* __restrict__ bb = b1 + qoff;
#pragma unroll
        for (int q = 0; q < 8; q++) h1[q] = bb[q];
    }
    if (active) {
        for (int pr = 0; pr < 3; pr++) {
            for (int pc = 0; pc < 3; pc++) {
                const int p9 = pr * 3 + pc;
                const float iv = s_img[(px + pr) * NPIX + (py + pc)];
                const float* __restrict__ wp = W1 + (p9 * 20) * 30 + qoff;
#pragma unroll
                for (int q = 0; q < 8; q++) h1[q] += iv * wp[q];
            }
        }
        const float posx = (float)(px - 16) * (1.0f / 16.0f);
        const float posy = (float)(py - 16) * (1.0f / 16.0f);
        const float* __restrict__ wx = W1 + 180 * 30 + qoff;
        const float* __restrict__ wy = W1 + 181 * 30 + qoff;
#pragma unroll
        for (int q = 0; q < 8; q++) h1[q] += posx * wx[q];
#pragma unroll
        for (int q = 0; q < 8; q++) h1[q] += posy * wy[q];
#pragma unroll
        for (int q = 0; q < 8; q++) h1[q] = fmaxf(h1[q], 0.0f);
#pragma unroll
        for (int q = 0; q < 8; q++) s_h[cell * HSTRIDE + qoff + q] = h1[q];
    }
    __syncthreads();

    float h2[8];
    {
        const float* __restrict__ bb = b2 + qoff;
#pragma unroll
        for (int q = 0; q < 8; q++) h2[q] = bb[q];
    }
    if (active) {
        float a1[30];
#pragma unroll
        for (int k = 0; k < 30; k++) a1[k] = s_h[cell * HSTRIDE + k];
        for (int k = 0; k < 30; k++) {
            const float* __restrict__ wr = W2 + k * 30 + qoff;
#pragma unroll
            for (int q = 0; q < 8; q++) h2[q] += a1[k] * wr[q];
        }
#pragma unroll
        for (int q = 0; q < 8; q++) h2[q] = fmaxf(h2[q], 0.0f);
    }
    __syncthreads();
    if (active) {
#pragma unroll
        for (int q = 0; q < 8; q++) s_h[cell * HSTRIDE + qoff + q] = h2[q];
    }
    __syncthreads();

    float o[6];
    {
        const float* __restrict__ bb = b3 + off3;
#pragma unroll
        for (int c = 0; c < 6; c++) o[c] = bb[c];
    }
    if (active) {
        float a2[30];
#pragma unroll
        for (int k = 0; k < 30; k++) a2[k] = s_h[cell * HSTRIDE + k];
        for (int k = 0; k < 30; k++) {
            const float* __restrict__ wr = W3 + k * 21 + off3;
#pragma unroll
            for (int c = 0; c < 6; c++) o[c] += a2[k] * wr[c];
        }
        float* __restrict__ ns =
            stateB + (((size_t)b * NPIX + (i + 1)) * NPIX + (j + 1)) * CPAD;
        if (qh == 0) {
#pragma unroll
            for (int c = 0; c < 6; c++) ns[c] = o[c];
        } else if (qh < 3) {
#pragma unroll
            for (int c = 1; c < 6; c++) ns[off3 + c] = o[c];
        } else {
#pragma unroll
            for (int c = 1; c < 4; c++) ns[15 + c] = o[c];
            int dxm = (o[4] > THRESHV) ? 1 : ((o[4] < -THRESHV) ? -1 : 0);
            int dym = (o[5] > THRESHV) ? 1 : ((o[5] < -THRESHV) ? -1 : 0);
            px += dxm; py += dym;
            px = (px < 0) ? 0 : ((px > NNEO - 1) ? NNEO - 1 : px);
            py = (py < 0) ? 0 : ((py > NNEO - 1) ? NNEO - 1 : py);
            perc[2 * gcell + 0] = px;
            perc[2 * gcell + 1] = py;
        }
    }
}

// ---------------------------------------------------------------------------
// Steps 1..9. R11 structure (CPAD=20, b128 fv), NEW this round: the 9-position
// layer-1 loop is software-pipelined with prefetch distance 1 (ping-pong
// fvA/fvB) — position p+1's 5 ds_read_b128 are issued before position p's
// ~320-cycle MAC block, so the lgkm drain completes under compute.
// The 19-row ch loop stays SOURCE-ROLLED inside each position (proven s_load
// codegen — R4/R6/R8: never pragma-unroll the weight loops).
// Accumulation order is bitwise-identical to R11.
// ---------------------------------------------------------------------------
#define LOADFV(dst, P) do {                                                    \
    const float4* __restrict__ sp4 =                                           \
        (const float4*)&s_state[(pix0 + ((P) / 3) * NPIX + ((P) % 3)) * CPAD]; \
    *(float4*)&dst[0]  = sp4[0];                                               \
    *(float4*)&dst[4]  = sp4[1];                                               \
    *(float4*)&dst[8]  = sp4[2];                                               \
    *(float4*)&dst[12] = sp4[3];                                               \
    *(float4*)&dst[16] = sp4[4];                                               \
} while (0)

#define MACPOS(fv, P) do {                                                     \
    const float iv = s_img[ib0 + ((P) / 3) * NPIX + ((P) % 3)];                \
    const float* __restrict__ wp = W1 + ((P) * 20) * 30 + qoff;                \
    _Pragma("unroll")                                                          \
    for (int q = 0; q < 8; q++) h1[q] += iv * wp[q];                           \
    for (int ch = 0; ch < CSTATE; ch++) {                                      \
        const float* __restrict__ wr = wp + (ch + 1) * 30;                     \
        _Pragma("unroll")                                                      \
        for (int q = 0; q < 8; q++) h1[q] += fv[ch] * wr[q];                   \
    }                                                                          \
} while (0)

template<bool LAST>
__global__ __launch_bounds__(1024, 8)
void nca_step(const float* __restrict__ img,
              const float* __restrict__ W1, const float* __restrict__ b1,
              const float* __restrict__ W2, const float* __restrict__ b2,
              const float* __restrict__ W3, const float* __restrict__ b3,
              const float* __restrict__ state_old, float* __restrict__ state_new,
              int* perc, float* __restrict__ guesses_out,
              float* __restrict__ class_out) {
    __shared__ float s_state[10 * NPIX * CPAD];     // 6400 floats = 25.6 KB
    __shared__ float s_img[NPIX * NPIX];            // 4 KB
    __shared__ float s_h[240 * HSTRIDE];            // 29.8 KB

    const int b   = blockIdx.y;
    const int rg  = blockIdx.x;
    const int i0  = (rg < 2) ? rg * 8 : 16 + (rg - 2) * 7;
    const int nr  = (rg < 2) ? 8 : 7;
    const int tid = threadIdx.x;
    const int qh  = __builtin_amdgcn_readfirstlane(tid >> 8);   // wave-uniform
    const int cell = tid & 255;
    const int qoff = (qh == 0) ? 0 : (qh == 1) ? 8 : (qh == 2) ? 14 : 22;
    const int off3 = 5 * qh;

    {
        const int n4 = (nr + 2) * NPIX * CPAD / 4;   // 1440 or 1600
        const float4* gstate4 =
            (const float4*)(state_old + ((size_t)b * NPIX + i0) * NPIX * CPAD);
        float4* s_state4 = (float4*)s_state;
        for (int t = tid; t < n4; t += 1024) s_state4[t] = gstate4[t];
    }
    if (tid < NPIX * NPIX / 4) {
        ((float4*)s_img)[tid] = ((const float4*)(img + (size_t)b * NPIX * NPIX))[tid];
    }
    __syncthreads();

    const int cells = nr * NNEO;
    const bool active = cell < cells;

    int r = 0, j = 0, i = 0, gcell = 0, px = 0, py = 0;
    if (active) {
        r = cell / NNEO;
        j = cell % NNEO;
        i = i0 + r;
        gcell = (b * NNEO + i) * NNEO + j;
        px = perc[2 * gcell]; py = perc[2 * gcell + 1];
    }

    // ---------------- layer 1: 182 -> 30 (this thread: 8 @ qoff) ----------
    float h1[8];
    {
        const float* __restrict__ bb = b1 + qoff;
#pragma unroll
        for (int q = 0; q < 8; q++) h1[q] = bb[q];
    }
    if (active) {
        const int pix0 = r * NPIX + j;       // cell's pixel in the LDS slab
        const int ib0  = px * NPIX + py;     // perceived pixel in the image
        float fvA[20], fvB[20];
        // 9-position pipeline, prefetch distance 1 (ping-pong buffers).
        LOADFV(fvA, 0);
        LOADFV(fvB, 1); MACPOS(fvA, 0);
        LOADFV(fvA, 2); MACPOS(fvB, 1);
        LOADFV(fvB, 3); MACPOS(fvA, 2);
        LOADFV(fvA, 4); MACPOS(fvB, 3);
        LOADFV(fvB, 5); MACPOS(fvA, 4);
        LOADFV(fvA, 6); MACPOS(fvB, 5);
        LOADFV(fvB, 7); MACPOS(fvA, 6);
        LOADFV(fvA, 8); MACPOS(fvB, 7);
        MACPOS(fvA, 8);

        const float posx = (float)(px - 16) * (1.0f / 16.0f);
        const float posy = (float)(py - 16) * (1.0f / 16.0f);
        const float* __restrict__ wx = W1 + 180 * 30 + qoff;
        const float* __restrict__ wy = W1 + 181 * 30 + qoff;
#pragma unroll
        for (int q = 0; q < 8; q++) h1[q] += posx * wx[q];
#pragma unroll
        for (int q = 0; q < 8; q++) h1[q] += posy * wy[q];
#pragma unroll
        for (int q = 0; q < 8; q++) h1[q] = fmaxf(h1[q], 0.0f);
#pragma unroll
        for (int q = 0; q < 8; q++) s_h[cell * HSTRIDE + qoff + q] = h1[q];
    }
    __syncthreads();

    // ---------------- layer 2: 30 -> 30 (this thread: 8 @ qoff) -----------
    float h2[8];
    {
        const float* __restrict__ bb = b2 + qoff;
#pragma unroll
        for (int q = 0; q < 8; q++) h2[q] = bb[q];
    }
    if (active) {
        float a1[30];
#pragma unroll
        for (int k = 0; k < 30; k++) a1[k] = s_h[cell * HSTRIDE + k];
        for (int k = 0; k < 30; k++) {
            const float* __restrict__ wr = W2 + k * 30 + qoff;
#pragma unroll
            for (int q = 0; q < 8; q++) h2[q] += a1[k] * wr[q];
        }
#pragma unroll
        for (int q = 0; q < 8; q++) h2[q] = fmaxf(h2[q], 0.0f);
    }
    __syncthreads();   // all a1 reads done before overwrite
    if (active) {
#pragma unroll
        for (int q = 0; q < 8; q++) s_h[cell * HSTRIDE + qoff + q] = h2[q];
    }
    __syncthreads();

    // ---------------- layer 3: 30 -> 21 (this thread: 6 @ off3) -----------
    float o[6];
    {
        const float* __restrict__ bb = b3 + off3;
#pragma unroll
        for (int c = 0; c < 6; c++) o[c] = bb[c];
    }
    if (active) {
        float a2[30];
#pragma unroll
        for (int k = 0; k < 30; k++) a2[k] = s_h[cell * HSTRIDE + k];
        for (int k = 0; k < 30; k++) {
            const float* __restrict__ wr = W3 + k * 21 + off3;
#pragma unroll
            for (int c = 0; c < 6; c++) o[c] += a2[k] * wr[c];
        }

        const int lcenter = ((r + 1) * NPIX + (j + 1)) * CPAD;
        if (!LAST) {
            float* __restrict__ ns =
                state_new + (((size_t)b * NPIX + (i + 1)) * NPIX + (j + 1)) * CPAD;
            // disjoint channel slices: q0 -> ch0-5, q1 -> ch6-10,
            // q2 -> ch11-15, q3 -> ch16-18 + movement (ch19,20 = o[4],o[5])
            if (qh == 0) {
#pragma unroll
                for (int c = 0; c < 6; c++)
                    ns[c] = s_state[lcenter + c] + o[c];
            } else if (qh < 3) {
#pragma unroll
                for (int c = 1; c < 6; c++)
                    ns[off3 + c] = s_state[lcenter + off3 + c] + o[c];
            } else {
#pragma unroll
                for (int c = 1; c < 4; c++)
                    ns[15 + c] = s_state[lcenter + 15 + c] + o[c];
                int dxm = (o[4] > THRESHV) ? 1 : ((o[4] < -THRESHV) ? -1 : 0);
                int dym = (o[5] > THRESHV) ? 1 : ((o[5] < -THRESHV) ? -1 : 0);
                px += dxm; py += dym;
                px = (px < 0) ? 0 : ((px > NNEO - 1) ? NNEO - 1 : px);
                py = (py < 0) ? 0 : ((py > NNEO - 1) ? NNEO - 1 : py);
                perc[2 * gcell + 0] = px;
                perc[2 * gcell + 1] = py;
            }
        } else {
            float* __restrict__ g = guesses_out + (size_t)gcell * OUTD;
            if (qh == 0) {
#pragma unroll
                for (int c = 0; c < 6; c++) g[c] = o[c];
            } else {
#pragma unroll
                for (int c = 1; c < 6; c++) g[off3 + c] = o[c];
            }
            if (qh == 3) {
                float* __restrict__ cs = class_out + (size_t)gcell * 3;
#pragma unroll
                for (int cc = 0; cc < 3; cc++)
                    cs[cc] = s_state[lcenter + 16 + cc] + o[1 + cc];
            }
        }
    }
}

extern "C" void kernel_launch(void* const* d_in, const int* in_sizes, int n_in,
                              void* d_out, int out_size, void* d_ws, size_t ws_size,
                              hipStream_t stream) {
    const float* img = (const float*)d_in[0];
    const float* W1  = (const float*)d_in[1];
    const float* b1  = (const float*)d_in[2];
    const float* W2  = (const float*)d_in[3];
    const float* b2  = (const float*)d_in[4];
    const float* W3  = (const float*)d_in[5];
    const float* b3  = (const float*)d_in[6];

    float* out = (float*)d_out;
    float* class_out   = out;                 // 345,600 floats
    float* guesses_out = out + CLASS_ELEMS;   // 2,419,200 floats

    float* stateA = (float*)d_ws;
    float* stateB = stateA + STATE_ELEMS_PAD;
    int*   perc   = (int*)(stateB + STATE_ELEMS_PAD);

    const dim3 grid(4, B_);
    // t = 0: standalone kernel; zeroes borders of both buffers (merged init),
    // writes stateB interior, sets perc
    nca_step0<<<grid, 1024, 0, stream>>>(img, W1, b1, W2, b2, W3, b3,
                                         stateA, stateB, perc);
    // t = 1..8: mid steps
    for (int t = 1; t < ITERS - 1; t++) {
        const float* so = (t & 1) ? stateB : stateA;
        float*       sn = (t & 1) ? stateA : stateB;
        nca_step<false><<<grid, 1024, 0, stream>>>(
            img, W1, b1, W2, b2, W3, b3, so, sn, perc, guesses_out, class_out);
    }
    // t = 9 (odd): reads stateB, emits outputs only
    nca_step<true><<<grid, 1024, 0, stream>>>(
        img, W1, b1, W2, b2, W3, b3, stateB, stateA, perc, guesses_out, class_out);
}

// Round 13
// 357.865 us; speedup vs baseline: 1.1974x; 1.1974x over previous
//
#include <hip/hip_runtime.h>

// Problem constants (from reference)
#define B_      128
#define NPIX    32      // N = M = 32
#define NNEO    30      // N-2
#define CSTATE  19      // real state channels
#define CPAD    20      // padded channel stride (16B-aligned pixel blocks)
#define OUTD    21      // OUT_DIM
#define ITERS   10
#define THRESHV 0.0007f

#define STATE_ELEMS_PAD (B_ * NPIX * NPIX * CPAD)  // 2,621,440 floats per buffer
#define NCELLS      (B_ * NNEO * NNEO)             // 115,200
#define CLASS_ELEMS (NCELLS * 3)                   // 345,600
#define HSTRIDE 31    // h-buffer cell stride: gcd(31,32)=1 -> conflict-free

// ---------------------------------------------------------------------------
// Step 0 standalone (R9/R10: removes the FIRST-template instantiation that
// kept drawing degenerate register allocations). State all-zero at t=0.
// Also zeroes the borders of BOTH state buffers (merged init, R12-proven).
// ---------------------------------------------------------------------------
__global__ __launch_bounds__(1024, 8)
void nca_step0(const float* __restrict__ img,
               const float* __restrict__ W1, const float* __restrict__ b1,
               const float* __restrict__ W2, const float* __restrict__ b2,
               const float* __restrict__ W3, const float* __restrict__ b3,
               float* __restrict__ stateA, float* __restrict__ stateB,
               int* __restrict__ perc) {
    __shared__ float s_img[NPIX * NPIX];            // 4 KB
    __shared__ float s_h[240 * HSTRIDE];            // 29.8 KB

    const int b   = blockIdx.y;
    const int rg  = blockIdx.x;
    const int i0  = (rg < 2) ? rg * 8 : 16 + (rg - 2) * 7;
    const int nr  = (rg < 2) ? 8 : 7;
    const int tid = threadIdx.x;
    const int qh  = __builtin_amdgcn_readfirstlane(tid >> 8);   // wave-uniform
    const int cell = tid & 255;
    const int qoff = (qh == 0) ? 0 : (qh == 1) ? 8 : (qh == 2) ? 14 : 22;
    const int off3 = 5 * qh;

    // merged init: zero borders of both buffers (124 pixels * 20 ch, /4 blocks)
    {
        const int per = (124 * CPAD) / 4;   // 620
        if (tid < per) {
            int idx = rg * per + tid;       // 0..2479
            int c    = idx % CPAD;
            int bc   = idx / CPAD;          // border cell 0..123
            int bi, bj;
            if (bc < 32)      { bi = 0;  bj = bc; }
            else if (bc < 64) { bi = 31; bj = bc - 32; }
            else { int k = bc - 64; bi = 1 + (k >> 1); bj = (k & 1) ? 31 : 0; }
            size_t off = (((size_t)b * NPIX + bi) * NPIX + bj) * CPAD + c;
            stateA[off] = 0.0f;
            stateB[off] = 0.0f;
        }
    }

    if (tid < NPIX * NPIX / 4) {
        ((float4*)s_img)[tid] = ((const float4*)(img + (size_t)b * NPIX * NPIX))[tid];
    }
    __syncthreads();

    const int cells = nr * NNEO;
    const bool active = cell < cells;

    int r = 0, j = 0, i = 0, gcell = 0, px = 0, py = 0;
    if (active) {
        r = cell / NNEO;
        j = cell % NNEO;
        i = i0 + r;
        gcell = (b * NNEO + i) * NNEO + j;
        px = i; py = j;
    }

    float h1[8];
    {
        const float* __restrict__ bb = b1 + qoff;
#pragma unroll
        for (int q = 0; q < 8; q++) h1[q] = bb[q];
    }
    if (active) {
        for (int pr = 0; pr < 3; pr++) {
            for (int pc = 0; pc < 3; pc++) {
                const int p9 = pr * 3 + pc;
                const float iv = s_img[(px + pr) * NPIX + (py + pc)];
                const float* __restrict__ wp = W1 + (p9 * 20) * 30 + qoff;
#pragma unroll
                for (int q = 0; q < 8; q++) h1[q] += iv * wp[q];
            }
        }
        const float posx = (float)(px - 16) * (1.0f / 16.0f);
        const float posy = (float)(py - 16) * (1.0f / 16.0f);
        const float* __restrict__ wx = W1 + 180 * 30 + qoff;
        const float* __restrict__ wy = W1 + 181 * 30 + qoff;
#pragma unroll
        for (int q = 0; q < 8; q++) h1[q] += posx * wx[q];
#pragma unroll
        for (int q = 0; q < 8; q++) h1[q] += posy * wy[q];
#pragma unroll
        for (int q = 0; q < 8; q++) h1[q] = fmaxf(h1[q], 0.0f);
#pragma unroll
        for (int q = 0; q < 8; q++) s_h[cell * HSTRIDE + qoff + q] = h1[q];
    }
    __syncthreads();

    float h2[8];
    {
        const float* __restrict__ bb = b2 + qoff;
#pragma unroll
        for (int q = 0; q < 8; q++) h2[q] = bb[q];
    }
    if (active) {
        float a1[30];
#pragma unroll
        for (int k = 0; k < 30; k++) a1[k] = s_h[cell * HSTRIDE + k];
        for (int k = 0; k < 30; k++) {
            const float* __restrict__ wr = W2 + k * 30 + qoff;
#pragma unroll
            for (int q = 0; q < 8; q++) h2[q] += a1[k] * wr[q];
        }
#pragma unroll
        for (int q = 0; q < 8; q++) h2[q] = fmaxf(h2[q], 0.0f);
    }
    __syncthreads();
    if (active) {
#pragma unroll
        for (int q = 0; q < 8; q++) s_h[cell * HSTRIDE + qoff + q] = h2[q];
    }
    __syncthreads();

    float o[6];
    {
        const float* __restrict__ bb = b3 + off3;
#pragma unroll
        for (int c = 0; c < 6; c++) o[c] = bb[c];
    }
    if (active) {
        float a2[30];
#pragma unroll
        for (int k = 0; k < 30; k++) a2[k] = s_h[cell * HSTRIDE + k];
        for (int k = 0; k < 30; k++) {
            const float* __restrict__ wr = W3 + k * 21 + off3;
#pragma unroll
            for (int c = 0; c < 6; c++) o[c] += a2[k] * wr[c];
        }
        float* __restrict__ ns =
            stateB + (((size_t)b * NPIX + (i + 1)) * NPIX + (j + 1)) * CPAD;
        if (qh == 0) {
#pragma unroll
            for (int c = 0; c < 6; c++) ns[c] = o[c];
        } else if (qh < 3) {
#pragma unroll
            for (int c = 1; c < 6; c++) ns[off3 + c] = o[c];
        } else {
#pragma unroll
            for (int c = 1; c < 4; c++) ns[15 + c] = o[c];
            int dxm = (o[4] > THRESHV) ? 1 : ((o[4] < -THRESHV) ? -1 : 0);
            int dym = (o[5] > THRESHV) ? 1 : ((o[5] < -THRESHV) ? -1 : 0);
            px += dxm; py += dym;
            px = (px < 0) ? 0 : ((px > NNEO - 1) ? NNEO - 1 : px);
            py = (py < 0) ? 0 : ((py > NNEO - 1) ? NNEO - 1 : py);
            perc[2 * gcell + 0] = px;
            perc[2 * gcell + 1] = py;
        }
    }
}

// ---------------------------------------------------------------------------
// Steps 1..9. Body = R11's proven kernel (CPAD=20, b128 fv burst, ALL weight
// loops rolled — R6/R8/R12: any unroll/pipeline over the 64-VGPR budget
// collapses the allocator). NEW this round: 3 barriers instead of 4 via a
// manual LDS pool — h2 goes to s_h2 aliased over the s_state+s_img region
// (dead after layer 1; the epilogue's center-state values are hoisted into
// 6 registers during layer 1), so the a1-consumed barrier disappears.
// Phase map: [stage s_state,s_img | B1 | layer1 reads them, preload cs,
// publish h1->s_h | B2 | layer2 reads s_h, writes s_h2 (alias) | B3 |
// layer3 reads s_h2, epilogue uses cs regs].
// ---------------------------------------------------------------------------
template<bool LAST>
__global__ __launch_bounds__(1024, 8)
void nca_step(const float* __restrict__ img,
              const float* __restrict__ W1, const float* __restrict__ b1,
              const float* __restrict__ W2, const float* __restrict__ b2,
              const float* __restrict__ W3, const float* __restrict__ b3,
              const float* __restrict__ state_old, float* __restrict__ state_new,
              int* perc, float* __restrict__ guesses_out,
              float* __restrict__ class_out) {
    // pool region 1: 7440 floats = s_state[6400] + s_img[1024] (phase A),
    //                re-used as s_h2[240*31] (phase B)
    // pool region 2: 7440 floats = s_h (h1)
    __shared__ float pool[7440 + 7440];             // 59.5 KB
    float* s_state = pool;                          // [0, 6400)
    float* s_img   = pool + 6400;                   // [6400, 7424)
    float* s_h2    = pool;                          // [0, 7439)  phase B alias
    float* s_h     = pool + 7440;                   // [7440, 14880)

    const int b   = blockIdx.y;
    const int rg  = blockIdx.x;
    const int i0  = (rg < 2) ? rg * 8 : 16 + (rg - 2) * 7;
    const int nr  = (rg < 2) ? 8 : 7;
    const int tid = threadIdx.x;
    const int qh  = __builtin_amdgcn_readfirstlane(tid >> 8);   // wave-uniform
    const int cell = tid & 255;
    const int qoff = (qh == 0) ? 0 : (qh == 1) ? 8 : (qh == 2) ? 14 : 22;
    const int off3 = 5 * qh;

    {
        const int n4 = (nr + 2) * NPIX * CPAD / 4;   // 1440 or 1600
        const float4* gstate4 =
            (const float4*)(state_old + ((size_t)b * NPIX + i0) * NPIX * CPAD);
        float4* s_state4 = (float4*)s_state;
        for (int t = tid; t < n4; t += 1024) s_state4[t] = gstate4[t];
    }
    if (tid < NPIX * NPIX / 4) {
        ((float4*)s_img)[tid] = ((const float4*)(img + (size_t)b * NPIX * NPIX))[tid];
    }
    __syncthreads();   // B1

    const int cells = nr * NNEO;
    const bool active = cell < cells;

    int r = 0, j = 0, i = 0, gcell = 0, px = 0, py = 0;
    if (active) {
        r = cell / NNEO;
        j = cell % NNEO;
        i = i0 + r;
        gcell = (b * NNEO + i) * NNEO + j;
        px = perc[2 * gcell]; py = perc[2 * gcell + 1];
    }

    // ---------------- layer 1: 182 -> 30 (this thread: 8 @ qoff) ----------
    float h1[8];
    {
        const float* __restrict__ bb = b1 + qoff;
#pragma unroll
        for (int q = 0; q < 8; q++) h1[q] = bb[q];
    }
    float cs[6];   // hoisted center-state values for the epilogue
    const int lcenter = ((r + 1) * NPIX + (j + 1)) * CPAD;
    if (active) {
        const int pix0 = r * NPIX + j;
        for (int pr = 0; pr < 3; pr++) {
            for (int pc = 0; pc < 3; pc++) {
                const int p9 = pr * 3 + pc;
                const float iv = s_img[(px + pr) * NPIX + (py + pc)];
                const float* __restrict__ wp = W1 + (p9 * 20) * 30 + qoff;
                // fv burst: 5 x ds_read_b128 (pixel block is 16B-aligned)
                const int sbase = (pix0 + pr * NPIX + pc) * CPAD;
                float fv[20];
                {
                    const float4* __restrict__ sp = (const float4*)&s_state[sbase];
#pragma unroll
                    for (int v = 0; v < 5; v++) *(float4*)&fv[4 * v] = sp[v];
                }
                // row 0: image feature
#pragma unroll
                for (int q = 0; q < 8; q++) h1[q] += iv * wp[q];
                // rows 1..19: state channels (rolled — keep s_load path)
                for (int ch = 0; ch < CSTATE; ch++) {
                    const float* __restrict__ wr = wp + (ch + 1) * 30;
#pragma unroll
                    for (int q = 0; q < 8; q++) h1[q] += fv[ch] * wr[q];
                }
            }
        }
        const float posx = (float)(px - 16) * (1.0f / 16.0f);
        const float posy = (float)(py - 16) * (1.0f / 16.0f);
        const float* __restrict__ wx = W1 + 180 * 30 + qoff;
        const float* __restrict__ wy = W1 + 181 * 30 + qoff;
#pragma unroll
        for (int q = 0; q < 8; q++) h1[q] += posx * wx[q];
#pragma unroll
        for (int q = 0; q < 8; q++) h1[q] += posy * wy[q];
#pragma unroll
        for (int q = 0; q < 8; q++) h1[q] = fmaxf(h1[q], 0.0f);
        // hoist center state for the epilogue (s_state dies at B2).
        // cs[c] = state[center][off3 + c]; qh3's c=4,5 may touch the next
        // pixel's pad floats — in-bounds, values unused.
#pragma unroll
        for (int c = 0; c < 6; c++) cs[c] = s_state[lcenter + off3 + c];
        // publish my slice of h1
#pragma unroll
        for (int q = 0; q < 8; q++) s_h[cell * HSTRIDE + qoff + q] = h1[q];
    }
    __syncthreads();   // B2 — all s_state/s_img reads complete before s_h2 writes

    // ---------------- layer 2: 30 -> 30 (this thread: 8 @ qoff) -----------
    float h2[8];
    {
        const float* __restrict__ bb = b2 + qoff;
#pragma unroll
        for (int q = 0; q < 8; q++) h2[q] = bb[q];
    }
    if (active) {
        float a1[30];
#pragma unroll
        for (int k = 0; k < 30; k++) a1[k] = s_h[cell * HSTRIDE + k];
        for (int k = 0; k < 30; k++) {
            const float* __restrict__ wr = W2 + k * 30 + qoff;
#pragma unroll
            for (int q = 0; q < 8; q++) h2[q] += a1[k] * wr[q];
        }
#pragma unroll
        for (int q = 0; q < 8; q++) h2[q] = fmaxf(h2[q], 0.0f);
        // publish h2 into the aliased buffer (no extra barrier needed)
#pragma unroll
        for (int q = 0; q < 8; q++) s_h2[cell * HSTRIDE + qoff + q] = h2[q];
    }
    __syncthreads();   // B3

    // ---------------- layer 3: 30 -> 21 (this thread: 6 @ off3) -----------
    float o[6];
    {
        const float* __restrict__ bb = b3 + off3;
#pragma unroll
        for (int c = 0; c < 6; c++) o[c] = bb[c];
    }
    if (active) {
        float a2[30];
#pragma unroll
        for (int k = 0; k < 30; k++) a2[k] = s_h2[cell * HSTRIDE + k];
        for (int k = 0; k < 30; k++) {
            const float* __restrict__ wr = W3 + k * 21 + off3;
#pragma unroll
            for (int c = 0; c < 6; c++) o[c] += a2[k] * wr[c];
        }

        if (!LAST) {
            float* __restrict__ ns =
                state_new + (((size_t)b * NPIX + (i + 1)) * NPIX + (j + 1)) * CPAD;
            // disjoint channel slices: q0 -> ch0-5, q1 -> ch6-10,
            // q2 -> ch11-15, q3 -> ch16-18 + movement (ch19,20 = o[4],o[5])
            if (qh == 0) {
#pragma unroll
                for (int c = 0; c < 6; c++) ns[c] = cs[c] + o[c];
            } else if (qh < 3) {
#pragma unroll
                for (int c = 1; c < 6; c++) ns[off3 + c] = cs[c] + o[c];
            } else {
#pragma unroll
                for (int c = 1; c < 4; c++) ns[15 + c] = cs[c] + o[c];
                int dxm = (o[4] > THRESHV) ? 1 : ((o[4] < -THRESHV) ? -1 : 0);
                int dym = (o[5] > THRESHV) ? 1 : ((o[5] < -THRESHV) ? -1 : 0);
                px += dxm; py += dym;
                px = (px < 0) ? 0 : ((px > NNEO - 1) ? NNEO - 1 : px);
                py = (py < 0) ? 0 : ((py > NNEO - 1) ? NNEO - 1 : py);
                perc[2 * gcell + 0] = px;
                perc[2 * gcell + 1] = py;
            }
        } else {
            float* __restrict__ g = guesses_out + (size_t)gcell * OUTD;
            if (qh == 0) {
#pragma unroll
                for (int c = 0; c < 6; c++) g[c] = o[c];
            } else {
#pragma unroll
                for (int c = 1; c < 6; c++) g[off3 + c] = o[c];
            }
            if (qh == 3) {
                // class channels 16..18 = center state + o[1..3]
                float* __restrict__ csp = class_out + (size_t)gcell * 3;
#pragma unroll
                for (int cc = 0; cc < 3; cc++)
                    csp[cc] = cs[1 + cc] + o[1 + cc];
            }
        }
    }
}

extern "C" void kernel_launch(void* const* d_in, const int* in_sizes, int n_in,
                              void* d_out, int out_size, void* d_ws, size_t ws_size,
                              hipStream_t stream) {
    const float* img = (const float*)d_in[0];
    const float* W1  = (const float*)d_in[1];
    const float* b1  = (const float*)d_in[2];
    const float* W2  = (const float*)d_in[3];
    const float* b2  = (const float*)d_in[4];
    const float* W3  = (const float*)d_in[5];
    const float* b3  = (const float*)d_in[6];

    float* out = (float*)d_out;
    float* class_out   = out;                 // 345,600 floats
    float* guesses_out = out + CLASS_ELEMS;   // 2,419,200 floats

    float* stateA = (float*)d_ws;
    float* stateB = stateA + STATE_ELEMS_PAD;
    int*   perc   = (int*)(stateB + STATE_ELEMS_PAD);

    const dim3 grid(4, B_);
    // t = 0: standalone kernel; zeroes borders of both buffers (merged init),
    // writes stateB interior, sets perc
    nca_step0<<<grid, 1024, 0, stream>>>(img, W1, b1, W2, b2, W3, b3,
                                         stateA, stateB, perc);
    // t = 1..8: mid steps
    for (int t = 1; t < ITERS - 1; t++) {
        const float* so = (t & 1) ? stateB : stateA;
        float*       sn = (t & 1) ? stateA : stateB;
        nca_step<false><<<grid, 1024, 0, stream>>>(
            img, W1, b1, W2, b2, W3, b3, so, sn, perc, guesses_out, class_out);
    }
    // t = 9 (odd): reads stateB, emits outputs only
    nca_step<true><<<grid, 1024, 0, stream>>>(
        img, W1, b1, W2, b2, W3, b3, stateB, stateA, perc, guesses_out, class_out);
}